// Round 11
// baseline (1262.631 us; speedup 1.0000x reference)
//
#include <hip/hip_runtime.h>
#include <hip/hip_bf16.h>
#include <math.h>

#define HC 256
#define NH 8
#define NEG_SLOPE 0.2f
#define CHW 64   // edges per chunk per wave (aggregation)

typedef unsigned short u16;
typedef __attribute__((ext_vector_type(8))) short bf16x8;
typedef __attribute__((ext_vector_type(4))) short bf16x4;
typedef __attribute__((ext_vector_type(4))) float f32x4;

__device__ __forceinline__ u16 f2bf(float f) {
    unsigned int u = __float_as_uint(f);
    u += 0x7FFFu + ((u >> 16) & 1u);
    return (u16)(u >> 16);
}
__device__ __forceinline__ float bf2f(u16 s) {
    return __uint_as_float(((unsigned int)s) << 16);
}
__device__ __forceinline__ f32x4 bf4f(ushort4 v) {
    f32x4 r;
    r[0] = bf2f(v.x); r[1] = bf2f(v.y); r[2] = bf2f(v.z); r[3] = bf2f(v.w);
    return r;
}

// raw barrier: own LDS writes drained -> all-wave barrier -> no read hoisting.
// Global loads in flight are NOT drained (unlike __syncthreads' vmcnt(0)).
#define BAR_LDS()                                                  \
    do {                                                           \
        asm volatile("s_waitcnt lgkmcnt(0)" ::: "memory");         \
        __builtin_amdgcn_s_barrier();                              \
        __builtin_amdgcn_sched_barrier(0);                         \
    } while (0)

// ---------------------------------------------------------------------------
// pack B (fp32 [K x 256]) -> hi/lo, fragment-major:
// chunk g = kt*1024 + f*64 + lane; col = f*16 + (lane&15); k = kt*32+(lane>>4)*8+e
// ---------------------------------------------------------------------------
__global__ __launch_bounds__(256) void pack_b_split(const float* __restrict__ B, int K,
                                                    u16* __restrict__ Bh,
                                                    u16* __restrict__ Bl) {
    const int g = blockIdx.x * 256 + threadIdx.x;
    const int lane = g & 63;
    const int f = (g >> 6) & 15;
    const int kt = g >> 10;
    const int col = f * 16 + (lane & 15);
    const int k0 = kt * 32 + (lane >> 4) * 8;
    bf16x8 hv, lv;
#pragma unroll
    for (int e = 0; e < 8; e++) {
        const float v = B[(size_t)(k0 + e) * HC + col];
        const u16 h = f2bf(v);
        hv[e] = (short)h;
        lv[e] = (short)f2bf(v - bf2f(h));
    }
    const size_t off = (size_t)g * 8;
    *(bf16x8*)(Bh + off) = hv;
    *(bf16x8*)(Bl + off) = lv;
}

// ---------------------------------------------------------------------------
// Fused MFMA GEMM: C = Ah*(Bh + Bl). 256 threads / 4 waves; tile M=64, N=256.
// Latency-pipelined: ring-4 LDS buffers, raw barriers (1 per 2 k-tiles, no
// vmcnt drain), A prefetched 2 tiles ahead in 2 register sets, B dbuf in regs.
// k-loop unrolled x4 with static buffer indices. Requires KT % 4 == 0.
// ---------------------------------------------------------------------------
__global__ __launch_bounds__(256, 4) void gemm_fused_split(
    const float* __restrict__ A,
    const u16* __restrict__ Bh, const u16* __restrict__ Bl,
    float* __restrict__ C, int M, int K) {
    __shared__ u16 ldsA[4][64 * 40];   // padded: row stride 40 u16 = 80 B
    const int tid = threadIdx.x;
    const int wid = tid >> 6;        // 0..3
    const int lane = tid & 63;
    const int rowblk = blockIdx.x;
    const int KT = K >> 5;           // 40 or 8 (divisible by 4)

    f32x4 acc[4][4];
#pragma unroll
    for (int i = 0; i < 4; i++)
#pragma unroll
        for (int j = 0; j < 4; j++) acc[i][j] = (f32x4)0.f;

    // coalesced staging map: thread t -> row t>>2, cols (t&3)*8 .. +7
    const int srow = tid >> 2;
    const int sc0 = (tid & 3) * 8;
    const int grow = rowblk * 64 + srow;
    const float* aptr = (grow < M) ? (A + (size_t)grow * K + sc0) : nullptr;
    const int woff = srow * 40 + sc0;

    auto loadA = [&](int kt, float4& v0, float4& v1) {
        v0 = make_float4(0.f, 0.f, 0.f, 0.f);
        v1 = v0;
        if (aptr && kt < KT) {
            v0 = *(const float4*)(aptr + kt * 32);
            v1 = *(const float4*)(aptr + kt * 32 + 4);
        }
    };
    auto stage = [&](u16* buf, float4 v0, float4 v1) {
        const float vv[8] = {v0.x, v0.y, v0.z, v0.w, v1.x, v1.y, v1.z, v1.w};
        bf16x8 hv;
#pragma unroll
        for (int e = 0; e < 8; e++) hv[e] = (short)f2bf(vv[e]);
        *(bf16x8*)&buf[woff] = hv;
    };
    auto readA = [&](const u16* buf, bf16x8* ah) {
#pragma unroll
        for (int i = 0; i < 4; i++)
            ah[i] = *(const bf16x8*)&buf[(i * 16 + (lane & 15)) * 40 + (lane >> 4) * 8];
    };
    auto loadB = [&](int kt, bf16x8* bh, bf16x8* bl) {
        if (kt >= KT) return;
        const u16* bHp = Bh + ((size_t)kt * 16 + wid * 4) * 512 + lane * 8;
        const u16* bLp = Bl + ((size_t)kt * 16 + wid * 4) * 512 + lane * 8;
#pragma unroll
        for (int j = 0; j < 4; j++) {
            bh[j] = *(const bf16x8*)(bHp + j * 512);
            bl[j] = *(const bf16x8*)(bLp + j * 512);
        }
    };
    auto mfma_tile = [&](const bf16x8* ah, const bf16x8* bh, const bf16x8* bl) {
#pragma unroll
        for (int i = 0; i < 4; i++)
#pragma unroll
            for (int j = 0; j < 4; j++) {
                acc[i][j] = __builtin_amdgcn_mfma_f32_16x16x32_bf16(ah[i], bh[j], acc[i][j], 0, 0, 0);
                acc[i][j] = __builtin_amdgcn_mfma_f32_16x16x32_bf16(ah[i], bl[j], acc[i][j], 0, 0, 0);
            }
    };

    // ---- preamble: bufs 0,1 staged; pf regs hold tiles 2,3 (in flight) ----
    float4 pAa, pAb, pBa, pBb;
    loadA(0, pAa, pAb);
    loadA(1, pBa, pBb);
    stage(ldsA[0], pAa, pAb);
    stage(ldsA[1], pBa, pBb);
    loadA(2, pAa, pAb);
    loadA(3, pBa, pBb);
    bf16x8 bhA[4], blA[4], bhB[4], blB[4];
    loadB(0, bhA, blA);
    BAR_LDS();

    for (int kt0 = 0; kt0 < KT; kt0 += 4) {
        const bool notLast = (kt0 + 4 < KT);
        bf16x8 ah[4];

        // phase 1: tile kt0 (buf0); stage tile kt0+2 -> buf2; issue pA <- kt0+4
        loadB(kt0 + 1, bhB, blB);
        readA(ldsA[0], ah);
        stage(ldsA[2], pAa, pAb);
        loadA(kt0 + 4, pAa, pAb);
        mfma_tile(ah, bhA, blA);

        // phase 2: tile kt0+1 (buf1); stage kt0+3 -> buf3; issue pB <- kt0+5
        loadB(kt0 + 2, bhA, blA);
        readA(ldsA[1], ah);
        stage(ldsA[3], pBa, pBb);
        loadA(kt0 + 5, pBa, pBb);
        mfma_tile(ah, bhB, blB);
        BAR_LDS();

        // phase 3: tile kt0+2 (buf2); stage kt0+4 -> buf0; issue pA <- kt0+6
        loadB(kt0 + 3, bhB, blB);
        readA(ldsA[2], ah);
        if (notLast) stage(ldsA[0], pAa, pAb);
        loadA(kt0 + 6, pAa, pAb);
        mfma_tile(ah, bhA, blA);

        // phase 4: tile kt0+3 (buf3); stage kt0+5 -> buf1; issue pB <- kt0+7
        loadB(kt0 + 4, bhA, blA);
        readA(ldsA[3], ah);
        if (notLast) stage(ldsA[1], pBa, pBb);
        loadA(kt0 + 7, pBa, pBb);
        mfma_tile(ah, bhB, blB);
        BAR_LDS();
    }

    // epilogue: C/D layout col = lane&15, row = (lane>>4)*4 + r
    const int r0 = rowblk * 64;
    const int colb = wid * 64 + (lane & 15);
#pragma unroll
    for (int i = 0; i < 4; i++) {
#pragma unroll
        for (int r = 0; r < 4; r++) {
            const int row = r0 + i * 16 + (lane >> 4) * 4 + r;
            if (row < M) {
#pragma unroll
                for (int j = 0; j < 4; j++)
                    C[(size_t)row * HC + colb + j * 16] = acc[i][j][r];
            }
        }
    }
}

// ---------------------------------------------------------------------------
// Per-node attention coefficients + bf16 copy of h for the gather
// ---------------------------------------------------------------------------
__global__ __launch_bounds__(256) void attn_coef(const float* __restrict__ h,
                                                 const float* __restrict__ att_s,
                                                 const float* __restrict__ att_d,
                                                 float* __restrict__ a_src,
                                                 float* __restrict__ a_dst,
                                                 u16* __restrict__ h_bf) {
    const int n = blockIdx.x;
    const int tid = threadIdx.x;
    const float hv = h[(size_t)n * HC + tid];
    h_bf[(size_t)n * HC + tid] = f2bf(hv);
    float p = hv * att_s[tid];
    float q = hv * att_d[tid];
#pragma unroll
    for (int m = 16; m >= 1; m >>= 1) {
        p += __shfl_xor(p, m);
        q += __shfl_xor(q, m);
    }
    if ((tid & 31) == 0) {
        a_src[n * NH + (tid >> 5)] = p;
        a_dst[n * NH + (tid >> 5)] = q;
    }
}

// ---------------------------------------------------------------------------
// CSR build: count, two-level scan, scatter (stores resolved src ids)
// ---------------------------------------------------------------------------
__global__ void count_deg(const int* __restrict__ dst, int E, int ET, int* __restrict__ deg) {
    const int e = blockIdx.x * blockDim.x + threadIdx.x;
    if (e >= ET) return;
    const int d = (e < E) ? dst[e] : (e - E);
    atomicAdd(&deg[d], 1);
}

__global__ __launch_bounds__(256) void scan_block(const int* __restrict__ deg,
                                                  int* __restrict__ row_ptr,
                                                  int* __restrict__ partials, int N) {
    __shared__ int sd[256];
    const int tid = threadIdx.x;
    const int base = blockIdx.x * 1024 + tid * 4;
    int v0 = (base + 0 < N) ? deg[base + 0] : 0;
    int v1 = (base + 1 < N) ? deg[base + 1] : 0;
    int v2 = (base + 2 < N) ? deg[base + 2] : 0;
    int v3 = (base + 3 < N) ? deg[base + 3] : 0;
    const int tsum = v0 + v1 + v2 + v3;
    sd[tid] = tsum;
    __syncthreads();
    int run = tsum;
    for (int off = 1; off < 256; off <<= 1) {
        int t = 0;
        if (tid >= off) t = sd[tid - off];
        __syncthreads();
        run += t;
        sd[tid] = run;
        __syncthreads();
    }
    const int excl = run - tsum;
    int s0 = excl + v0, s1 = s0 + v1, s2 = s1 + v2, s3 = s2 + v3;
    if (base + 0 < N) row_ptr[base + 1] = s0;
    if (base + 1 < N) row_ptr[base + 2] = s1;
    if (base + 2 < N) row_ptr[base + 3] = s2;
    if (base + 3 < N) row_ptr[base + 4] = s3;
    if (tid == 255) partials[blockIdx.x] = run;
}

__global__ __launch_bounds__(1024) void scan_partials(int* __restrict__ partials, int nb) {
    __shared__ int sd[1024];
    const int tid = threadIdx.x;
    int v = (tid < nb) ? partials[tid] : 0;
    sd[tid] = v;
    __syncthreads();
    int run = v;
    for (int off = 1; off < 1024; off <<= 1) {
        int t = 0;
        if (tid >= off) t = sd[tid - off];
        __syncthreads();
        run += t;
        sd[tid] = run;
        __syncthreads();
    }
    if (tid < nb) partials[tid] = run - v;  // exclusive
}

__global__ __launch_bounds__(256) void scan_add(int* __restrict__ row_ptr,
                                                const int* __restrict__ partials, int N) {
    const int i = blockIdx.x * 256 + threadIdx.x;
    if (i == 0) row_ptr[0] = 0;
    if (i < N) row_ptr[i + 1] += partials[i >> 10];
}

__global__ void scatter_edges(const int* __restrict__ src_in, const int* __restrict__ dst,
                              int E, int ET, const int* __restrict__ row_ptr,
                              int* __restrict__ cursor, int* __restrict__ esrc) {
    const int e = blockIdx.x * blockDim.x + threadIdx.x;
    if (e >= ET) return;
    const int d = (e < E) ? dst[e] : (e - E);
    const int s = (e < E) ? src_in[e] : (e - E);
    const int pos = atomicAdd(&cursor[d], 1);
    esrc[row_ptr[d] + pos] = s;
}

// ---------------------------------------------------------------------------
// GAT aggregation, one WAVE per dst node. Gather reads bf16 h rows (512B/row).
// ---------------------------------------------------------------------------
__global__ __launch_bounds__(256) void gat_aggregate_wave(
    const u16* __restrict__ h_bf, const float* __restrict__ a_src,
    const float* __restrict__ a_dst, const int* __restrict__ row_ptr,
    const int* __restrict__ esrc, const float* __restrict__ bias,
    float* __restrict__ out, int N) {
    __shared__ int   s_src[4][CHW];
    __shared__ float s_ev[4][CHW][NH];

    const int tid = threadIdx.x;
    const int wv = tid >> 6;
    const int lane = tid & 63;
    const int n = blockIdx.x * 4 + wv;
    if (n >= N) return;

    const int beg = row_ptr[n];
    const int deg = row_ptr[n + 1] - beg;
    const int jj = lane >> 3;   // edge slot 0..7
    const int hh = lane & 7;    // head for softmax lanes
    const int g4 = lane >> 3;   // head for gather features

    const float adh = a_dst[n * NH + hh];
    float m_run = -1e30f, d_run = 0.f;
    f32x4 acc = (f32x4)0.f;

    for (int c0 = 0; c0 < deg; c0 += CHW) {
        const int chlen = min(CHW, deg - c0);

        float lmax = -1e30f;
        for (int p = 0; p < chlen; p += 8) {
            const int j = p + jj;
            if (j < chlen) {
                const int s = esrc[beg + c0 + j];
                if (hh == 0) s_src[wv][j] = s;
                float v = a_src[s * NH + hh] + adh;
                v = (v > 0.f) ? v : NEG_SLOPE * v;
                s_ev[wv][j][hh] = v;
                lmax = fmaxf(lmax, v);
            }
        }
        lmax = fmaxf(lmax, __shfl_xor(lmax, 8));
        lmax = fmaxf(lmax, __shfl_xor(lmax, 16));
        lmax = fmaxf(lmax, __shfl_xor(lmax, 32));
        const float mo = m_run;
        const float mn = fmaxf(mo, lmax);
        const float scl = __expf(mo - mn);
        m_run = mn;

        float lsum = 0.f;
        for (int p = 0; p < chlen; p += 8) {
            const int j = p + jj;
            if (j < chlen) {
                const float pv = __expf(s_ev[wv][j][hh] - mn);
                s_ev[wv][j][hh] = pv;
                lsum += pv;
            }
        }
        lsum += __shfl_xor(lsum, 8);
        lsum += __shfl_xor(lsum, 16);
        lsum += __shfl_xor(lsum, 32);
        d_run = d_run * scl + lsum;

        __asm__ volatile("s_waitcnt lgkmcnt(0)" ::: "memory");

        const float scl4 = __shfl(scl, g4);
        f32x4 t0 = (f32x4)0.f, t1 = (f32x4)0.f, t2 = (f32x4)0.f, t3 = (f32x4)0.f;
        int j = 0;
        for (; j + 4 <= chlen; j += 4) {
            const int s0 = s_src[wv][j],     s1 = s_src[wv][j + 1];
            const int s2 = s_src[wv][j + 2], s3 = s_src[wv][j + 3];
            const float p0 = s_ev[wv][j][g4],     p1 = s_ev[wv][j + 1][g4];
            const float p2 = s_ev[wv][j + 2][g4], p3 = s_ev[wv][j + 3][g4];
            const f32x4 h0 = bf4f(*(const ushort4*)&h_bf[(size_t)s0 * HC + lane * 4]);
            const f32x4 h1 = bf4f(*(const ushort4*)&h_bf[(size_t)s1 * HC + lane * 4]);
            const f32x4 h2 = bf4f(*(const ushort4*)&h_bf[(size_t)s2 * HC + lane * 4]);
            const f32x4 h3 = bf4f(*(const ushort4*)&h_bf[(size_t)s3 * HC + lane * 4]);
#pragma unroll
            for (int q = 0; q < 4; q++) {
                t0[q] += p0 * h0[q];
                t1[q] += p1 * h1[q];
                t2[q] += p2 * h2[q];
                t3[q] += p3 * h3[q];
            }
        }
        for (; j < chlen; j++) {
            const int s0 = s_src[wv][j];
            const float p0 = s_ev[wv][j][g4];
            const f32x4 h0 = bf4f(*(const ushort4*)&h_bf[(size_t)s0 * HC + lane * 4]);
#pragma unroll
            for (int q = 0; q < 4; q++) t0[q] += p0 * h0[q];
        }
#pragma unroll
        for (int q = 0; q < 4; q++)
            acc[q] = acc[q] * scl4 + ((t0[q] + t1[q]) + (t2[q] + t3[q]));
    }

    const float invd = 1.f / (__shfl(d_run, g4) + 1e-16f);
    const f32x4 bv = *(const f32x4*)&bias[lane * 4];
    f32x4 o;
#pragma unroll
    for (int q = 0; q < 4; q++) o[q] = fmaxf(acc[q] * invd + bv[q], 0.f);
    *(f32x4*)&out[(size_t)n * HC + lane * 4] = o;
}

// ---------------------------------------------------------------------------
// Pooling stage 1
// ---------------------------------------------------------------------------
__global__ __launch_bounds__(256) void pool_partial(const float* __restrict__ h,
                                                    const int* __restrict__ batch, int N,
                                                    float* __restrict__ sums) {
    __shared__ int bs[64];
    const int tid = threadIdx.x;
    const int base = blockIdx.x * 64;
    const int cnt = min(64, N - base);
    if (tid < 64 && tid < cnt) bs[tid] = batch[base + tid];
    __syncthreads();

    float acc = 0.f;
    int cur = bs[0];
    for (int i = 0; i < cnt; i++) {
        const int g = bs[i];
        if (g != cur) {
            atomicAdd(&sums[(size_t)cur * HC + tid], acc);
            acc = 0.f;
            cur = g;
        }
        acc += h[(size_t)(base + i) * HC + tid];
    }
    atomicAdd(&sums[(size_t)cur * HC + tid], acc);
}

__global__ __launch_bounds__(256) void pool_div(float* __restrict__ sums,
                                                const int* __restrict__ batch, int N) {
    const int g = blockIdx.x;
    const int tid = threadIdx.x;
    int lo = 0, hi = N;
    while (lo < hi) {
        const int mid = (lo + hi) >> 1;
        if (batch[mid] < g) lo = mid + 1; else hi = mid;
    }
    const int start = lo;
    hi = N;
    while (lo < hi) {
        const int mid = (lo + hi) >> 1;
        if (batch[mid] < g + 1) lo = mid + 1; else hi = mid;
    }
    const float inv = 1.f / fmaxf((float)(lo - start), 1.0f);
    sums[(size_t)g * HC + tid] *= inv;
}

// ---------------------------------------------------------------------------
// MLP head
// ---------------------------------------------------------------------------
__global__ __launch_bounds__(128) void mlp_head(const float* __restrict__ pooled,
                                                const float* __restrict__ w1,
                                                const float* __restrict__ b1,
                                                const float* __restrict__ w2,
                                                const float* __restrict__ b2,
                                                float* __restrict__ out) {
    const int g = blockIdx.x;
    const int tid = threadIdx.x;
    __shared__ float p[HC];
    p[tid] = pooled[g * HC + tid];
    p[tid + 128] = pooled[g * HC + tid + 128];
    __syncthreads();
    float z = b1[tid];
#pragma unroll 8
    for (int k = 0; k < HC; k++) z += p[k] * w1[k * 128 + tid];
    z = fmaxf(z, 0.f);
    float t = z * w2[tid];
#pragma unroll
    for (int m = 32; m >= 1; m >>= 1) t += __shfl_xor(t, m);
    __shared__ float ws2[2];
    if ((tid & 63) == 0) ws2[tid >> 6] = t;
    __syncthreads();
    if (tid == 0) out[g] = ws2[0] + ws2[1] + b2[0];
}

// ---------------------------------------------------------------------------
// Host-side launcher
// ---------------------------------------------------------------------------
extern "C" void kernel_launch(void* const* d_in, const int* in_sizes, int n_in,
                              void* d_out, int out_size, void* d_ws, size_t ws_size,
                              hipStream_t stream) {
    const float* x      = (const float*)d_in[0];
    const int*   ei     = (const int*)d_in[1];
    const int*   batch  = (const int*)d_in[2];
    const float* W1     = (const float*)d_in[3];
    const float* as1    = (const float*)d_in[4];
    const float* ad1    = (const float*)d_in[5];
    const float* b1     = (const float*)d_in[6];
    const float* W2     = (const float*)d_in[7];
    const float* as2    = (const float*)d_in[8];
    const float* ad2    = (const float*)d_in[9];
    const float* b2     = (const float*)d_in[10];
    const float* lin1w  = (const float*)d_in[11];
    const float* lin1b  = (const float*)d_in[12];
    const float* lin2w  = (const float*)d_in[13];
    const float* lin2b  = (const float*)d_in[14];

    const int N   = in_sizes[2];       // 50000
    const int E   = in_sizes[1] / 2;   // 800000
    const int ET  = E + N;
    const int Fin = in_sizes[0] / N;   // 1280
    const int NG  = 64;

    const int nRB = (N + 63) / 64;
    const int nScanBlk = (N + 1023) / 1024;

    const int* src_arr = ei;
    const int* dst_arr = ei + E;

    char* ws = (char*)d_ws;
    size_t off = 0;
    auto alloc = [&](size_t bytes) {
        void* p = ws + off;
        off += (bytes + 255) & ~(size_t)255;
        return p;
    };
    float* h_gemm  = (float*)alloc((size_t)N * HC * sizeof(float));
    float* h_agg   = (float*)alloc((size_t)N * HC * sizeof(float));
    u16*   h_bf    = (u16*)alloc((size_t)N * HC * sizeof(u16));
    float* a_src   = (float*)alloc((size_t)N * NH * sizeof(float));
    float* a_dst   = (float*)alloc((size_t)N * NH * sizeof(float));
    int*   deg     = (int*)alloc((size_t)N * sizeof(int));
    int*   cursor  = (int*)alloc((size_t)N * sizeof(int));
    int*   row_ptr = (int*)alloc((size_t)(N + 1) * sizeof(int));
    int*   partials= (int*)alloc((size_t)1024 * sizeof(int));
    int*   esrc    = (int*)alloc((size_t)ET * sizeof(int));
    float* pooled  = (float*)alloc((size_t)NG * HC * sizeof(float));
    u16* Bh = (u16*)alloc((size_t)Fin * HC * sizeof(u16));
    u16* Bl = (u16*)alloc((size_t)Fin * HC * sizeof(u16));
    (void)ws_size; (void)n_in; (void)out_size;

    // ---- CSR build ----
    hipMemsetAsync(deg, 0, (size_t)N * sizeof(int), stream);
    hipMemsetAsync(cursor, 0, (size_t)N * sizeof(int), stream);
    {
        const int blocks = (ET + 255) / 256;
        count_deg<<<blocks, 256, 0, stream>>>(dst_arr, E, ET, deg);
        scan_block<<<nScanBlk, 256, 0, stream>>>(deg, row_ptr, partials, N);
        scan_partials<<<1, 1024, 0, stream>>>(partials, nScanBlk);
        scan_add<<<(N + 255) / 256, 256, 0, stream>>>(row_ptr, partials, N);
        scatter_edges<<<blocks, 256, 0, stream>>>(src_arr, dst_arr, E, ET, row_ptr,
                                                  cursor, esrc);
    }

    const int aggBlocks = (N + 3) / 4;

    // ---- Layer 1 ----
    pack_b_split<<<(Fin / 32) * 4, 256, 0, stream>>>(W1, Fin, Bh, Bl);
    gemm_fused_split<<<nRB, 256, 0, stream>>>(x, Bh, Bl, h_gemm, N, Fin);
    attn_coef<<<N, 256, 0, stream>>>(h_gemm, as1, ad1, a_src, a_dst, h_bf);
    gat_aggregate_wave<<<aggBlocks, 256, 0, stream>>>(h_bf, a_src, a_dst, row_ptr,
                                                      esrc, b1, h_agg, N);

    // ---- Layer 2 ----
    pack_b_split<<<(HC / 32) * 4, 256, 0, stream>>>(W2, HC, Bh, Bl);
    gemm_fused_split<<<nRB, 256, 0, stream>>>(h_agg, Bh, Bl, h_gemm, N, HC);
    attn_coef<<<N, 256, 0, stream>>>(h_gemm, as2, ad2, a_src, a_dst, h_bf);
    gat_aggregate_wave<<<aggBlocks, 256, 0, stream>>>(h_bf, a_src, a_dst, row_ptr,
                                                      esrc, b2, h_agg, N);

    // ---- Pool + MLP head ----
    hipMemsetAsync(pooled, 0, (size_t)NG * HC * sizeof(float), stream);
    pool_partial<<<(N + 63) / 64, 256, 0, stream>>>(h_agg, batch, N, pooled);
    pool_div<<<NG, 256, 0, stream>>>(pooled, batch, N);
    mlp_head<<<NG, 128, 0, stream>>>(pooled, lin1w, lin1b, lin2w, lin2b, (float*)d_out);
}

// Round 12
// 508.269 us; speedup vs baseline: 2.4842x; 2.4842x over previous
//
#include <hip/hip_runtime.h>
#include <hip/hip_bf16.h>
#include <math.h>

#define HC 256
#define NH 8
#define NEG_SLOPE 0.2f
#define CHW 64   // edges per chunk per wave (aggregation)

typedef unsigned short u16;
typedef __attribute__((ext_vector_type(8))) short bf16x8;
typedef __attribute__((ext_vector_type(4))) short bf16x4;
typedef __attribute__((ext_vector_type(4))) float f32x4;

__device__ __forceinline__ u16 f2bf(float f) {
    unsigned int u = __float_as_uint(f);
    u += 0x7FFFu + ((u >> 16) & 1u);
    return (u16)(u >> 16);
}
__device__ __forceinline__ float bf2f(u16 s) {
    return __uint_as_float(((unsigned int)s) << 16);
}
__device__ __forceinline__ f32x4 bf4f(ushort4 v) {
    f32x4 r;
    r[0] = bf2f(v.x); r[1] = bf2f(v.y); r[2] = bf2f(v.z); r[3] = bf2f(v.w);
    return r;
}

// raw barrier: own LDS writes drained -> all-wave barrier -> no read hoisting.
// Global loads in flight are NOT drained (unlike __syncthreads' vmcnt(0)).
// Safe for the dbuf pattern: each iteration reads buf cur / writes buf cur^1
// entirely before the barrier, so one barrier provides the same ordering.
#define BAR_LDS()                                                  \
    do {                                                           \
        asm volatile("s_waitcnt lgkmcnt(0)" ::: "memory");         \
        __builtin_amdgcn_s_barrier();                              \
        __builtin_amdgcn_sched_barrier(0);                         \
    } while (0)

// ---------------------------------------------------------------------------
// pack B (fp32 [K x 256]) -> hi/lo, fragment-major:
// chunk g = kt*1024 + f*64 + lane; col = f*16 + (lane&15); k = kt*32+(lane>>4)*8+e
// ---------------------------------------------------------------------------
__global__ __launch_bounds__(256) void pack_b_split(const float* __restrict__ B, int K,
                                                    u16* __restrict__ Bh,
                                                    u16* __restrict__ Bl) {
    const int g = blockIdx.x * 256 + threadIdx.x;
    const int lane = g & 63;
    const int f = (g >> 6) & 15;
    const int kt = g >> 10;
    const int col = f * 16 + (lane & 15);
    const int k0 = kt * 32 + (lane >> 4) * 8;
    bf16x8 hv, lv;
#pragma unroll
    for (int e = 0; e < 8; e++) {
        const float v = B[(size_t)(k0 + e) * HC + col];
        const u16 h = f2bf(v);
        hv[e] = (short)h;
        lv[e] = (short)f2bf(v - bf2f(h));
    }
    const size_t off = (size_t)g * 8;
    *(bf16x8*)(Bh + off) = hv;
    *(bf16x8*)(Bl + off) = lv;
}

// ---------------------------------------------------------------------------
// Fused MFMA GEMM: C = Ah*(Bh + Bl), A bf16-rounded once, B split.
// 256 threads / 4 waves. Tile M=64, N=256; wave w owns cols [w*64, w*64+64).
// Round-10 structure (116 VGPR, 2x5KB LDS dbuf, B reg-dbuf, 2-deep A prefetch)
// with ONLY the barrier changed: raw s_barrier without vmcnt drain, so the
// A/B global prefetches stay in flight across k-tiles.
// ---------------------------------------------------------------------------
__global__ __launch_bounds__(256) void gemm_fused_split(
    const float* __restrict__ A,
    const u16* __restrict__ Bh, const u16* __restrict__ Bl,
    float* __restrict__ C, int M, int K) {
    __shared__ u16 ldsA[2][64 * 40];   // padded: row stride 40 u16 = 80 B
    const int tid = threadIdx.x;
    const int wid = tid >> 6;        // 0..3
    const int lane = tid & 63;
    const int rowblk = blockIdx.x;
    const int KT = K >> 5;           // k-tiles of 32 (KT is even: 40 or 8)

    f32x4 acc[4][4];
#pragma unroll
    for (int i = 0; i < 4; i++)
#pragma unroll
        for (int j = 0; j < 4; j++) acc[i][j] = (f32x4)0.f;

    // coalesced staging map: thread t -> row t>>2, cols (t&3)*8 .. +7
    const int srow = tid >> 2;
    const int sc0 = (tid & 3) * 8;
    const int grow = rowblk * 64 + srow;
    const float* aptr = (grow < M) ? (A + (size_t)grow * K + sc0) : nullptr;
    const int woff = srow * 40 + sc0;   // u16 units, 16-B aligned

    auto stage = [&](int buf, float4 v0, float4 v1) {
        const float vv[8] = {v0.x, v0.y, v0.z, v0.w, v1.x, v1.y, v1.z, v1.w};
        bf16x8 hv;
#pragma unroll
        for (int e = 0; e < 8; e++) hv[e] = (short)f2bf(vv[e]);
        *(bf16x8*)&ldsA[buf][woff] = hv;
    };
    auto readA = [&](int buf, bf16x8* ah) {
#pragma unroll
        for (int i = 0; i < 4; i++)
            ah[i] = *(const bf16x8*)&ldsA[buf][(i * 16 + (lane & 15)) * 40 +
                                              (lane >> 4) * 8];
    };
    auto loadB = [&](int kt, bf16x8* bh, bf16x8* bl) {
        const u16* bHp = Bh + ((size_t)kt * 16 + wid * 4) * 512 + lane * 8;
        const u16* bLp = Bl + ((size_t)kt * 16 + wid * 4) * 512 + lane * 8;
#pragma unroll
        for (int j = 0; j < 4; j++) {
            bh[j] = *(const bf16x8*)(bHp + j * 512);
            bl[j] = *(const bf16x8*)(bLp + j * 512);
        }
    };
    auto mfma_tile = [&](const bf16x8* ah, const bf16x8* bh, const bf16x8* bl) {
#pragma unroll
        for (int i = 0; i < 4; i++)
#pragma unroll
            for (int j = 0; j < 4; j++) {
                acc[i][j] = __builtin_amdgcn_mfma_f32_16x16x32_bf16(ah[i], bh[j], acc[i][j], 0, 0, 0);
                acc[i][j] = __builtin_amdgcn_mfma_f32_16x16x32_bf16(ah[i], bl[j], acc[i][j], 0, 0, 0);
            }
    };

    float4 a0 = make_float4(0.f, 0.f, 0.f, 0.f), a1 = a0;
    if (aptr) {
        a0 = *(const float4*)(aptr);
        a1 = *(const float4*)(aptr + 4);
    }
    stage(0, a0, a1);                         // tile 0 -> buf 0
    a0 = make_float4(0.f, 0.f, 0.f, 0.f); a1 = a0;
    if (aptr && KT > 1) {                     // tile 1 -> regs
        a0 = *(const float4*)(aptr + 32);
        a1 = *(const float4*)(aptr + 36);
    }
    BAR_LDS();

    bf16x8 b0h[4], b0l[4], b1h[4], b1l[4];
    loadB(0, b0h, b0l);

    int cur = 0;
    for (int kt = 0; kt < KT; kt += 2) {
        // ---- subtile kt (B set 0) ----
        if (kt + 1 < KT) loadB(kt + 1, b1h, b1l);
        bf16x8 ah[4];
        readA(cur, ah);
        stage(cur ^ 1, a0, a1);               // tile kt+1 (kt+1 < KT since KT even)
        a0 = make_float4(0.f, 0.f, 0.f, 0.f); a1 = a0;
        if (aptr && kt + 2 < KT) {
            a0 = *(const float4*)(aptr + (kt + 2) * 32);
            a1 = *(const float4*)(aptr + (kt + 2) * 32 + 4);
        }
        mfma_tile(ah, b0h, b0l);
        BAR_LDS();
        cur ^= 1;

        // ---- subtile kt+1 (B set 1) ----
        if (kt + 2 < KT) loadB(kt + 2, b0h, b0l);
        readA(cur, ah);
        if (kt + 2 < KT) {
            stage(cur ^ 1, a0, a1);           // tile kt+2
            a0 = make_float4(0.f, 0.f, 0.f, 0.f); a1 = a0;
            if (aptr && kt + 3 < KT) {
                a0 = *(const float4*)(aptr + (kt + 3) * 32);
                a1 = *(const float4*)(aptr + (kt + 3) * 32 + 4);
            }
        }
        mfma_tile(ah, b1h, b1l);
        BAR_LDS();
        cur ^= 1;
    }

    // epilogue: C/D layout col = lane&15, row = (lane>>4)*4 + r
    const int r0 = rowblk * 64;
    const int colb = wid * 64 + (lane & 15);
#pragma unroll
    for (int i = 0; i < 4; i++) {
#pragma unroll
        for (int r = 0; r < 4; r++) {
            const int row = r0 + i * 16 + (lane >> 4) * 4 + r;
            if (row < M) {
#pragma unroll
                for (int j = 0; j < 4; j++)
                    C[(size_t)row * HC + colb + j * 16] = acc[i][j][r];
            }
        }
    }
}

// ---------------------------------------------------------------------------
// Per-node attention coefficients + bf16 copy of h for the gather
// ---------------------------------------------------------------------------
__global__ __launch_bounds__(256) void attn_coef(const float* __restrict__ h,
                                                 const float* __restrict__ att_s,
                                                 const float* __restrict__ att_d,
                                                 float* __restrict__ a_src,
                                                 float* __restrict__ a_dst,
                                                 u16* __restrict__ h_bf) {
    const int n = blockIdx.x;
    const int tid = threadIdx.x;
    const float hv = h[(size_t)n * HC + tid];
    h_bf[(size_t)n * HC + tid] = f2bf(hv);
    float p = hv * att_s[tid];
    float q = hv * att_d[tid];
#pragma unroll
    for (int m = 16; m >= 1; m >>= 1) {
        p += __shfl_xor(p, m);
        q += __shfl_xor(q, m);
    }
    if ((tid & 31) == 0) {
        a_src[n * NH + (tid >> 5)] = p;
        a_dst[n * NH + (tid >> 5)] = q;
    }
}

// ---------------------------------------------------------------------------
// CSR build: count, two-level scan, scatter (stores resolved src ids)
// ---------------------------------------------------------------------------
__global__ void count_deg(const int* __restrict__ dst, int E, int ET, int* __restrict__ deg) {
    const int e = blockIdx.x * blockDim.x + threadIdx.x;
    if (e >= ET) return;
    const int d = (e < E) ? dst[e] : (e - E);
    atomicAdd(&deg[d], 1);
}

__global__ __launch_bounds__(256) void scan_block(const int* __restrict__ deg,
                                                  int* __restrict__ row_ptr,
                                                  int* __restrict__ partials, int N) {
    __shared__ int sd[256];
    const int tid = threadIdx.x;
    const int base = blockIdx.x * 1024 + tid * 4;
    int v0 = (base + 0 < N) ? deg[base + 0] : 0;
    int v1 = (base + 1 < N) ? deg[base + 1] : 0;
    int v2 = (base + 2 < N) ? deg[base + 2] : 0;
    int v3 = (base + 3 < N) ? deg[base + 3] : 0;
    const int tsum = v0 + v1 + v2 + v3;
    sd[tid] = tsum;
    __syncthreads();
    int run = tsum;
    for (int off = 1; off < 256; off <<= 1) {
        int t = 0;
        if (tid >= off) t = sd[tid - off];
        __syncthreads();
        run += t;
        sd[tid] = run;
        __syncthreads();
    }
    const int excl = run - tsum;
    int s0 = excl + v0, s1 = s0 + v1, s2 = s1 + v2, s3 = s2 + v3;
    if (base + 0 < N) row_ptr[base + 1] = s0;
    if (base + 1 < N) row_ptr[base + 2] = s1;
    if (base + 2 < N) row_ptr[base + 3] = s2;
    if (base + 3 < N) row_ptr[base + 4] = s3;
    if (tid == 255) partials[blockIdx.x] = run;
}

__global__ __launch_bounds__(1024) void scan_partials(int* __restrict__ partials, int nb) {
    __shared__ int sd[1024];
    const int tid = threadIdx.x;
    int v = (tid < nb) ? partials[tid] : 0;
    sd[tid] = v;
    __syncthreads();
    int run = v;
    for (int off = 1; off < 1024; off <<= 1) {
        int t = 0;
        if (tid >= off) t = sd[tid - off];
        __syncthreads();
        run += t;
        sd[tid] = run;
        __syncthreads();
    }
    if (tid < nb) partials[tid] = run - v;  // exclusive
}

__global__ __launch_bounds__(256) void scan_add(int* __restrict__ row_ptr,
                                                const int* __restrict__ partials, int N) {
    const int i = blockIdx.x * 256 + threadIdx.x;
    if (i == 0) row_ptr[0] = 0;
    if (i < N) row_ptr[i + 1] += partials[i >> 10];
}

__global__ void scatter_edges(const int* __restrict__ src_in, const int* __restrict__ dst,
                              int E, int ET, const int* __restrict__ row_ptr,
                              int* __restrict__ cursor, int* __restrict__ esrc) {
    const int e = blockIdx.x * blockDim.x + threadIdx.x;
    if (e >= ET) return;
    const int d = (e < E) ? dst[e] : (e - E);
    const int s = (e < E) ? src_in[e] : (e - E);
    const int pos = atomicAdd(&cursor[d], 1);
    esrc[row_ptr[d] + pos] = s;
}

// ---------------------------------------------------------------------------
// GAT aggregation, one WAVE per dst node. Gather reads bf16 h rows (512B/row).
// ---------------------------------------------------------------------------
__global__ __launch_bounds__(256) void gat_aggregate_wave(
    const u16* __restrict__ h_bf, const float* __restrict__ a_src,
    const float* __restrict__ a_dst, const int* __restrict__ row_ptr,
    const int* __restrict__ esrc, const float* __restrict__ bias,
    float* __restrict__ out, int N) {
    __shared__ int   s_src[4][CHW];
    __shared__ float s_ev[4][CHW][NH];

    const int tid = threadIdx.x;
    const int wv = tid >> 6;
    const int lane = tid & 63;
    const int n = blockIdx.x * 4 + wv;
    if (n >= N) return;

    const int beg = row_ptr[n];
    const int deg = row_ptr[n + 1] - beg;
    const int jj = lane >> 3;   // edge slot 0..7
    const int hh = lane & 7;    // head for softmax lanes
    const int g4 = lane >> 3;   // head for gather features

    const float adh = a_dst[n * NH + hh];
    float m_run = -1e30f, d_run = 0.f;
    f32x4 acc = (f32x4)0.f;

    for (int c0 = 0; c0 < deg; c0 += CHW) {
        const int chlen = min(CHW, deg - c0);

        float lmax = -1e30f;
        for (int p = 0; p < chlen; p += 8) {
            const int j = p + jj;
            if (j < chlen) {
                const int s = esrc[beg + c0 + j];
                if (hh == 0) s_src[wv][j] = s;
                float v = a_src[s * NH + hh] + adh;
                v = (v > 0.f) ? v : NEG_SLOPE * v;
                s_ev[wv][j][hh] = v;
                lmax = fmaxf(lmax, v);
            }
        }
        lmax = fmaxf(lmax, __shfl_xor(lmax, 8));
        lmax = fmaxf(lmax, __shfl_xor(lmax, 16));
        lmax = fmaxf(lmax, __shfl_xor(lmax, 32));
        const float mo = m_run;
        const float mn = fmaxf(mo, lmax);
        const float scl = __expf(mo - mn);
        m_run = mn;

        float lsum = 0.f;
        for (int p = 0; p < chlen; p += 8) {
            const int j = p + jj;
            if (j < chlen) {
                const float pv = __expf(s_ev[wv][j][hh] - mn);
                s_ev[wv][j][hh] = pv;
                lsum += pv;
            }
        }
        lsum += __shfl_xor(lsum, 8);
        lsum += __shfl_xor(lsum, 16);
        lsum += __shfl_xor(lsum, 32);
        d_run = d_run * scl + lsum;

        __asm__ volatile("s_waitcnt lgkmcnt(0)" ::: "memory");

        const float scl4 = __shfl(scl, g4);
        f32x4 t0 = (f32x4)0.f, t1 = (f32x4)0.f, t2 = (f32x4)0.f, t3 = (f32x4)0.f;
        int j = 0;
        for (; j + 4 <= chlen; j += 4) {
            const int s0 = s_src[wv][j],     s1 = s_src[wv][j + 1];
            const int s2 = s_src[wv][j + 2], s3 = s_src[wv][j + 3];
            const float p0 = s_ev[wv][j][g4],     p1 = s_ev[wv][j + 1][g4];
            const float p2 = s_ev[wv][j + 2][g4], p3 = s_ev[wv][j + 3][g4];
            const f32x4 h0 = bf4f(*(const ushort4*)&h_bf[(size_t)s0 * HC + lane * 4]);
            const f32x4 h1 = bf4f(*(const ushort4*)&h_bf[(size_t)s1 * HC + lane * 4]);
            const f32x4 h2 = bf4f(*(const ushort4*)&h_bf[(size_t)s2 * HC + lane * 4]);
            const f32x4 h3 = bf4f(*(const ushort4*)&h_bf[(size_t)s3 * HC + lane * 4]);
#pragma unroll
            for (int q = 0; q < 4; q++) {
                t0[q] += p0 * h0[q];
                t1[q] += p1 * h1[q];
                t2[q] += p2 * h2[q];
                t3[q] += p3 * h3[q];
            }
        }
        for (; j < chlen; j++) {
            const int s0 = s_src[wv][j];
            const float p0 = s_ev[wv][j][g4];
            const f32x4 h0 = bf4f(*(const ushort4*)&h_bf[(size_t)s0 * HC + lane * 4]);
#pragma unroll
            for (int q = 0; q < 4; q++) t0[q] += p0 * h0[q];
        }
#pragma unroll
        for (int q = 0; q < 4; q++)
            acc[q] = acc[q] * scl4 + ((t0[q] + t1[q]) + (t2[q] + t3[q]));
    }

    const float invd = 1.f / (__shfl(d_run, g4) + 1e-16f);
    const f32x4 bv = *(const f32x4*)&bias[lane * 4];
    f32x4 o;
#pragma unroll
    for (int q = 0; q < 4; q++) o[q] = fmaxf(acc[q] * invd + bv[q], 0.f);
    *(f32x4*)&out[(size_t)n * HC + lane * 4] = o;
}

// ---------------------------------------------------------------------------
// Pooling stage 1
// ---------------------------------------------------------------------------
__global__ __launch_bounds__(256) void pool_partial(const float* __restrict__ h,
                                                    const int* __restrict__ batch, int N,
                                                    float* __restrict__ sums) {
    __shared__ int bs[64];
    const int tid = threadIdx.x;
    const int base = blockIdx.x * 64;
    const int cnt = min(64, N - base);
    if (tid < 64 && tid < cnt) bs[tid] = batch[base + tid];
    __syncthreads();

    float acc = 0.f;
    int cur = bs[0];
    for (int i = 0; i < cnt; i++) {
        const int g = bs[i];
        if (g != cur) {
            atomicAdd(&sums[(size_t)cur * HC + tid], acc);
            acc = 0.f;
            cur = g;
        }
        acc += h[(size_t)(base + i) * HC + tid];
    }
    atomicAdd(&sums[(size_t)cur * HC + tid], acc);
}

__global__ __launch_bounds__(256) void pool_div(float* __restrict__ sums,
                                                const int* __restrict__ batch, int N) {
    const int g = blockIdx.x;
    const int tid = threadIdx.x;
    int lo = 0, hi = N;
    while (lo < hi) {
        const int mid = (lo + hi) >> 1;
        if (batch[mid] < g) lo = mid + 1; else hi = mid;
    }
    const int start = lo;
    hi = N;
    while (lo < hi) {
        const int mid = (lo + hi) >> 1;
        if (batch[mid] < g + 1) lo = mid + 1; else hi = mid;
    }
    const float inv = 1.f / fmaxf((float)(lo - start), 1.0f);
    sums[(size_t)g * HC + tid] *= inv;
}

// ---------------------------------------------------------------------------
// MLP head
// ---------------------------------------------------------------------------
__global__ __launch_bounds__(128) void mlp_head(const float* __restrict__ pooled,
                                                const float* __restrict__ w1,
                                                const float* __restrict__ b1,
                                                const float* __restrict__ w2,
                                                const float* __restrict__ b2,
                                                float* __restrict__ out) {
    const int g = blockIdx.x;
    const int tid = threadIdx.x;
    __shared__ float p[HC];
    p[tid] = pooled[g * HC + tid];
    p[tid + 128] = pooled[g * HC + tid + 128];
    __syncthreads();
    float z = b1[tid];
#pragma unroll 8
    for (int k = 0; k < HC; k++) z += p[k] * w1[k * 128 + tid];
    z = fmaxf(z, 0.f);
    float t = z * w2[tid];
#pragma unroll
    for (int m = 32; m >= 1; m >>= 1) t += __shfl_xor(t, m);
    __shared__ float ws2[2];
    if ((tid & 63) == 0) ws2[tid >> 6] = t;
    __syncthreads();
    if (tid == 0) out[g] = ws2[0] + ws2[1] + b2[0];
}

// ---------------------------------------------------------------------------
// Host-side launcher
// ---------------------------------------------------------------------------
extern "C" void kernel_launch(void* const* d_in, const int* in_sizes, int n_in,
                              void* d_out, int out_size, void* d_ws, size_t ws_size,
                              hipStream_t stream) {
    const float* x      = (const float*)d_in[0];
    const int*   ei     = (const int*)d_in[1];
    const int*   batch  = (const int*)d_in[2];
    const float* W1     = (const float*)d_in[3];
    const float* as1    = (const float*)d_in[4];
    const float* ad1    = (const float*)d_in[5];
    const float* b1     = (const float*)d_in[6];
    const float* W2     = (const float*)d_in[7];
    const float* as2    = (const float*)d_in[8];
    const float* ad2    = (const float*)d_in[9];
    const float* b2     = (const float*)d_in[10];
    const float* lin1w  = (const float*)d_in[11];
    const float* lin1b  = (const float*)d_in[12];
    const float* lin2w  = (const float*)d_in[13];
    const float* lin2b  = (const float*)d_in[14];

    const int N   = in_sizes[2];       // 50000
    const int E   = in_sizes[1] / 2;   // 800000
    const int ET  = E + N;
    const int Fin = in_sizes[0] / N;   // 1280
    const int NG  = 64;

    const int nRB = (N + 63) / 64;
    const int nScanBlk = (N + 1023) / 1024;

    const int* src_arr = ei;
    const int* dst_arr = ei + E;

    char* ws = (char*)d_ws;
    size_t off = 0;
    auto alloc = [&](size_t bytes) {
        void* p = ws + off;
        off += (bytes + 255) & ~(size_t)255;
        return p;
    };
    float* h_gemm  = (float*)alloc((size_t)N * HC * sizeof(float));
    float* h_agg   = (float*)alloc((size_t)N * HC * sizeof(float));
    u16*   h_bf    = (u16*)alloc((size_t)N * HC * sizeof(u16));
    float* a_src   = (float*)alloc((size_t)N * NH * sizeof(float));
    float* a_dst   = (float*)alloc((size_t)N * NH * sizeof(float));
    int*   deg     = (int*)alloc((size_t)N * sizeof(int));
    int*   cursor  = (int*)alloc((size_t)N * sizeof(int));
    int*   row_ptr = (int*)alloc((size_t)(N + 1) * sizeof(int));
    int*   partials= (int*)alloc((size_t)1024 * sizeof(int));
    int*   esrc    = (int*)alloc((size_t)ET * sizeof(int));
    float* pooled  = (float*)alloc((size_t)NG * HC * sizeof(float));
    u16* Bh = (u16*)alloc((size_t)Fin * HC * sizeof(u16));
    u16* Bl = (u16*)alloc((size_t)Fin * HC * sizeof(u16));
    (void)ws_size; (void)n_in; (void)out_size;

    // ---- CSR build ----
    hipMemsetAsync(deg, 0, (size_t)N * sizeof(int), stream);
    hipMemsetAsync(cursor, 0, (size_t)N * sizeof(int), stream);
    {
        const int blocks = (ET + 255) / 256;
        count_deg<<<blocks, 256, 0, stream>>>(dst_arr, E, ET, deg);
        scan_block<<<nScanBlk, 256, 0, stream>>>(deg, row_ptr, partials, N);
        scan_partials<<<1, 1024, 0, stream>>>(partials, nScanBlk);
        scan_add<<<(N + 255) / 256, 256, 0, stream>>>(row_ptr, partials, N);
        scatter_edges<<<blocks, 256, 0, stream>>>(src_arr, dst_arr, E, ET, row_ptr,
                                                  cursor, esrc);
    }

    const int aggBlocks = (N + 3) / 4;

    // ---- Layer 1 ----
    pack_b_split<<<(Fin / 32) * 4, 256, 0, stream>>>(W1, Fin, Bh, Bl);
    gemm_fused_split<<<nRB, 256, 0, stream>>>(x, Bh, Bl, h_gemm, N, Fin);
    attn_coef<<<N, 256, 0, stream>>>(h_gemm, as1, ad1, a_src, a_dst, h_bf);
    gat_aggregate_wave<<<aggBlocks, 256, 0, stream>>>(h_bf, a_src, a_dst, row_ptr,
                                                      esrc, b1, h_agg, N);

    // ---- Layer 2 ----
    pack_b_split<<<(HC / 32) * 4, 256, 0, stream>>>(W2, HC, Bh, Bl);
    gemm_fused_split<<<nRB, 256, 0, stream>>>(h_agg, Bh, Bl, h_gemm, N, HC);
    attn_coef<<<N, 256, 0, stream>>>(h_gemm, as2, ad2, a_src, a_dst, h_bf);
    gat_aggregate_wave<<<aggBlocks, 256, 0, stream>>>(h_bf, a_src, a_dst, row_ptr,
                                                      esrc, b2, h_agg, N);

    // ---- Pool + MLP head ----
    hipMemsetAsync(pooled, 0, (size_t)NG * HC * sizeof(float), stream);
    pool_partial<<<(N + 63) / 64, 256, 0, stream>>>(h_agg, batch, N, pooled);
    pool_div<<<NG, 256, 0, stream>>>(pooled, batch, N);
    mlp_head<<<NG, 128, 0, stream>>>(pooled, lin1w, lin1b, lin2w, lin2b, (float*)d_out);
}